// Round 17
// baseline (163.562 us; speedup 1.0000x reference)
//
#include <hip/hip_runtime.h>
#include <hip/hip_bf16.h>
#include <stdint.h>

#define B_ 64
#define T_ 20
#define N_ 8192
#define E_ 128
#define H_ 128
#define G4 512

typedef short bf16x8 __attribute__((ext_vector_type(8)));
typedef float f32x4 __attribute__((ext_vector_type(4)));

__device__ __forceinline__ float sigmoidf_(float x){ return 1.0f/(1.0f+expf(-x)); }

__device__ __forceinline__ unsigned short f2bf(float f){
  union { float f; uint32_t u; } v; v.f = f;
  uint32_t u = v.u;
  uint32_t r = (u + 0x7FFFu + ((u >> 16) & 1u)) >> 16;
  return (unsigned short)r;
}
__device__ __forceinline__ uint32_t pk2(float a, float b){
  return (uint32_t)f2bf(a) | ((uint32_t)f2bf(b) << 16);
}
__device__ __forceinline__ float bf2f(unsigned short s){
  union { uint32_t u; float f; } v; v.u = ((uint32_t)s) << 16; return v.f;
}

// ---------------- 1. transpose W1,W2 -> W12T bf16 (R10 verbatim)
__global__ void k_transpose(const float* __restrict__ W1, const float* __restrict__ W2,
                            unsigned short* __restrict__ W12T){
  __shared__ float t1[128][33];
  __shared__ float t2[128][33];
  int n0 = blockIdx.x * 32;
  int tid = threadIdx.x;           // 256
  int nl = tid & 31, eg = tid >> 5;
  for (int i = 0; i < 16; i++){
    int e = eg * 16 + i;
    t1[e][nl] = W1[(size_t)e*N_ + n0 + nl];
    t2[e][nl] = W2[(size_t)e*N_ + n0 + nl];
  }
  __syncthreads();
  for (int n = 0; n < 32; n++){
    float v = (tid < 128) ? t1[tid][n] : t2[tid-128][n];
    W12T[(size_t)(n0+n)*256 + tid] = f2bf(v);
  }
}

// ---------------- 2. sparse MLP (R10 verbatim)
__global__ void k_mlp(const float* __restrict__ x, const int* __restrict__ seq_len,
                      const unsigned short* __restrict__ W12T, const float* __restrict__ b1,
                      const float* __restrict__ b2, float* __restrict__ basket){
  int bt = blockIdx.x;
  int b = bt / T_, t = bt % T_;
  int tid = threadIdx.x;           // 256
  if (t >= seq_len[b]){
    if (tid < 128) basket[(size_t)bt*E_ + tid] = 0.f;
    return;
  }
  __shared__ int idxs[1024];
  __shared__ int cnt;
  __shared__ float e2s[128];
  if (tid == 0) cnt = 0;
  __syncthreads();
  const float4* xr = (const float4*)(x + (size_t)bt * N_);
  for (int i = 0; i < 8; i++){
    float4 v = xr[i*256 + tid];
    int base = (i*256 + tid)*4;
    if (v.x != 0.f){ int q = atomicAdd(&cnt,1); idxs[q] = base;   }
    if (v.y != 0.f){ int q = atomicAdd(&cnt,1); idxs[q] = base+1; }
    if (v.z != 0.f){ int q = atomicAdd(&cnt,1); idxs[q] = base+2; }
    if (v.w != 0.f){ int q = atomicAdd(&cnt,1); idxs[q] = base+3; }
  }
  __syncthreads();
  int m = cnt; if (m > 1024) m = 1024;
  float acc = (tid < 128) ? b1[tid] : b2[tid-128];
  int i = 0;
  for (; i + 8 <= m; i += 8){
    int j0 = idxs[i+0], j1 = idxs[i+1], j2 = idxs[i+2], j3 = idxs[i+3];
    int j4 = idxs[i+4], j5 = idxs[i+5], j6 = idxs[i+6], j7 = idxs[i+7];
    float v0 = bf2f(W12T[(size_t)j0*256 + tid]);
    float v1 = bf2f(W12T[(size_t)j1*256 + tid]);
    float v2 = bf2f(W12T[(size_t)j2*256 + tid]);
    float v3 = bf2f(W12T[(size_t)j3*256 + tid]);
    float v4 = bf2f(W12T[(size_t)j4*256 + tid]);
    float v5 = bf2f(W12T[(size_t)j5*256 + tid]);
    float v6 = bf2f(W12T[(size_t)j6*256 + tid]);
    float v7 = bf2f(W12T[(size_t)j7*256 + tid]);
    acc += ((v0+v1)+(v2+v3)) + ((v4+v5)+(v6+v7));
  }
  for (; i < m; i++)
    acc += bf2f(W12T[(size_t)idxs[i]*256 + tid]);
  acc = fmaxf(acc, 0.f);
  if (tid >= 128) e2s[tid-128] = acc;
  __syncthreads();
  if (tid < 128) basket[(size_t)bt*E_ + tid] = fmaxf(acc, e2s[tid]);
}

// ---------------- 3. fused x-projection + LSTM (R10 lstmx verbatim)
__global__ void __launch_bounds__(512, 1)
k_lstmx(const int* __restrict__ seq_len, const float* __restrict__ basket,
        const float* __restrict__ W_ih, const float* __restrict__ b_ih,
        const float* __restrict__ b_hh, const float* __restrict__ W_hh,
        float* __restrict__ hn){
  int b = blockIdx.x;
  int L = seq_len[b];
  int j = threadIdx.x;              // 512
  __shared__ float bsk[T_][E_];
  __shared__ float XpL[T_][G4];
  __shared__ float hs[128];
  __shared__ float gs[512];
  for (int idx = j; idx < T_*E_; idx += 512)
    bsk[idx>>7][idx&127] = basket[((size_t)b*T_ + (idx>>7))*E_ + (idx&127)];
  __syncthreads();
  {
    float bias = b_ih[j] + b_hh[j];
    float accv[T_];
    #pragma unroll
    for (int tt = 0; tt < T_; tt++) accv[tt] = bias;
    const float4* wr = (const float4*)(W_ih + (size_t)j * E_);
    for (int k4 = 0; k4 < 32; k4++){
      float4 w = wr[k4];
      #pragma unroll
      for (int tt = 0; tt < T_; tt++){
        float4 h = *(const float4*)&bsk[tt][k4*4];
        accv[tt] += w.x*h.x + w.y*h.y + w.z*h.z + w.w*h.w;
      }
    }
    #pragma unroll
    for (int tt = 0; tt < T_; tt++) XpL[tt][j] = accv[tt];
  }
  float4 whh[32];
  const float4* wr2 = (const float4*)(W_hh + (size_t)j * H_);
  #pragma unroll
  for (int k = 0; k < 32; k++) whh[k] = wr2[k];
  if (j < 128) hs[j] = 0.f;
  float c = 0.f;
  __syncthreads();
  for (int t = 0; t < L; t++){
    float s0 = XpL[t][j], s1 = 0.f, s2 = 0.f, s3 = 0.f;
    #pragma unroll
    for (int k = 0; k < 32; k += 4){
      float4 w, h;
      w = whh[k+0]; h = *(const float4*)&hs[k*4+ 0]; s0 += w.x*h.x + w.y*h.y + w.z*h.z + w.w*h.w;
      w = whh[k+1]; h = *(const float4*)&hs[k*4+ 4]; s1 += w.x*h.x + w.y*h.y + w.z*h.z + w.w*h.w;
      w = whh[k+2]; h = *(const float4*)&hs[k*4+ 8]; s2 += w.x*h.x + w.y*h.y + w.z*h.z + w.w*h.w;
      w = whh[k+3]; h = *(const float4*)&hs[k*4+12]; s3 += w.x*h.x + w.y*h.y + w.z*h.z + w.w*h.w;
    }
    gs[j] = (s0 + s1) + (s2 + s3);
    __syncthreads();
    if (j < 128){
      float i_ = gs[j], f_ = gs[128+j], gg = gs[256+j], o_ = gs[384+j];
      c = sigmoidf_(f_)*c + sigmoidf_(i_)*tanhf(gg);
      hs[j] = sigmoidf_(o_)*tanhf(c);
    }
    __syncthreads();
  }
  if (j < 128) hn[(size_t)b*H_ + j] = hs[j];
}

// ---------------- 4. p = sigmoid(hn @ W_out^T) via MFMA -> bf16 (R10 verbatim)
__global__ void k_pout(const float* __restrict__ hn, const float* __restrict__ W_out,
                       unsigned short* __restrict__ pbf){
  __shared__ unsigned short hb[64*128];
  int tid = threadIdx.x;                  // 256
  {
    int row = tid >> 2;
    int k16 = (tid & 3) * 32;
    const float4* hr = (const float4*)(hn + (size_t)row*H_ + k16);
    #pragma unroll
    for (int i = 0; i < 4; i++){
      float4 a = hr[i*2], bq = hr[i*2+1];
      uint4 u; u.x = pk2(a.x,a.y); u.y = pk2(a.z,a.w); u.z = pk2(bq.x,bq.y); u.w = pk2(bq.z,bq.w);
      int blk = (k16 >> 3) + i;
      *(uint4*)&hb[row*128 + ((blk ^ (row & 7)) * 8)] = u;
    }
  }
  __syncthreads();
  int w = tid >> 6, l = tid & 63;
  int n0 = blockIdx.x * 128;
  f32x4 acc[8];
  #pragma unroll
  for (int i = 0; i < 8; i++) acc[i] = (f32x4){0.f,0.f,0.f,0.f};
  int row = w*16 + (l & 15);
  #pragma unroll
  for (int ks = 0; ks < 4; ks++){
    int kk = ks*32 + (l >> 4)*8;
    int blk = kk >> 3;
    bf16x8 af = *(bf16x8*)&hb[row*128 + ((blk ^ (row & 7)) * 8)];
    #pragma unroll
    for (int nt = 0; nt < 8; nt++){
      int n = n0 + nt*16 + (l & 15);
      const float4* wp = (const float4*)(W_out + (size_t)n*H_ + kk);
      float4 wa = wp[0], wb = wp[1];
      union { uint4 u; bf16x8 v; } cc;
      cc.u.x = pk2(wa.x,wa.y); cc.u.y = pk2(wa.z,wa.w);
      cc.u.z = pk2(wb.x,wb.y); cc.u.w = pk2(wb.z,wb.w);
      acc[nt] = __builtin_amdgcn_mfma_f32_16x16x32_bf16(af, cc.v, acc[nt], 0, 0, 0);
    }
  }
  #pragma unroll
  for (int nt = 0; nt < 8; nt++){
    int n = n0 + nt*16 + (l & 15);
    #pragma unroll
    for (int r = 0; r < 4; r++){
      int rr = w*16 + (l >> 4)*4 + r;
      float pv = 1.f/(1.f + expf(-acc[nt][r]));
      pbf[(size_t)rr*N_ + n] = f2bf(pv);
    }
  }
}

// ---------------- 5. out = blend(p, p @ A) — SPLITN, full-K, fused epilogue
// 256 blocks x 512 thr; block nb owns out[:, nb*32 .. nb*32+32) exclusively.
// BK=128, NSTEP=64, 2-deep issue-ahead dbuf; named registers only.
#define ISSUEF(q0,q1,r0,r1,kb) do {                                            \
    r0 = *(const uint4*)&pbf[(size_t)prow*N_ + (kb) + c8*8];                   \
    r1 = *(const uint4*)&pbf[(size_t)prow*N_ + (kb) + 64 + c8*8];              \
    const float* bse = Ag + (size_t)((kb) + kq*8)*N_ + n0 + sn;                \
    q0.x = bse[0];               q0.y = bse[(size_t)N_];                       \
    q0.z = bse[2*(size_t)N_];    q0.w = bse[3*(size_t)N_];                     \
    q1.x = bse[4*(size_t)N_];    q1.y = bse[5*(size_t)N_];                     \
    q1.z = bse[6*(size_t)N_];    q1.w = bse[7*(size_t)N_];                     \
  } while(0)

#define STAGEF(abf,ptb,q0,q1,r0,r1) do {                                       \
    *(uint4*)&ptb[prow*128 + ((c8*8) ^ swp)]        = r0;                      \
    *(uint4*)&ptb[prow*128 + ((64 + c8*8) ^ swp)]   = r1;                      \
    uint4 v; v.x = pk2(q0.x,q0.y); v.y = pk2(q0.z,q0.w);                       \
    v.z = pk2(q1.x,q1.y); v.w = pk2(q1.z,q1.w);                                \
    *(uint4*)&abf[sn*128 + ((kq*8) ^ swa)] = v;                                \
  } while(0)

#define SYNC_AND() do {                                                        \
    asm volatile("s_waitcnt lgkmcnt(0)" ::: "memory");                         \
    __builtin_amdgcn_sched_barrier(0);                                         \
    __builtin_amdgcn_s_barrier();                                              \
    __builtin_amdgcn_sched_barrier(0);                                         \
  } while(0)

__global__ void __launch_bounds__(512, 4)
k_gemmf(const unsigned short* __restrict__ pbf, const float* __restrict__ Ag,
        const float* __restrict__ I_B, float* __restrict__ out){
  __shared__ unsigned short abf0[32*128];   // A tile [n][k] bf16, 8 KB
  __shared__ unsigned short abf1[32*128];
  __shared__ unsigned short pt0[64*128];    // p tile [m][k] bf16, 16 KB
  __shared__ unsigned short pt1[64*128];
  int tid = threadIdx.x;                    // 512
  int nb = blockIdx.x;                      // 256 blocks
  int n0 = nb * 32;
  int sn = tid & 31, kq = tid >> 5;         // A staging: 32 n x 16 k-groups(8)
  int prow = tid >> 3, c8 = tid & 7;        // p staging: 64 m x 8 k-groups(8)
  int swp = (prow & 7) * 8;
  int swa = (sn & 7) * 8;
  int w = tid >> 6, l = tid & 63;
  int wm = w >> 1, wn = w & 1;              // 4x2 waves over 64x32 tile
  f32x4 acc = {0.f, 0.f, 0.f, 0.f};
  const int NSTEP = N_ / 128;               // 64

  f32x4 aA0, aA1, aB0, aB1;
  uint4 pA0, pA1, pB0, pB1;

  int m_  = wm*16 + (l & 15);
  int nn_ = wn*16 + (l & 15);
  int swm = (m_ & 7) * 8;
  int swn = (nn_ & 7) * 8;

  auto compute = [&](const unsigned short* abf, const unsigned short* ptb){
    #pragma unroll
    for (int kc = 0; kc < 128; kc += 32){
      int ko = kc + (l >> 4)*8;
      bf16x8 af = *(const bf16x8*)&ptb[m_*128 + (ko ^ swm)];
      bf16x8 bf = *(const bf16x8*)&abf[nn_*128 + (ko ^ swn)];
      acc = __builtin_amdgcn_mfma_f32_16x16x32_bf16(af, bf, acc, 0, 0, 0);
    }
  };

  ISSUEF(aA0,aA1,pA0,pA1, 0);
  for (int s = 0; s < NSTEP; s += 2){
    if (s + 1 < NSTEP) ISSUEF(aB0,aB1,pB0,pB1, (s+1)*128);
    STAGEF(abf0, pt0, aA0,aA1, pA0,pA1);
    SYNC_AND();
    compute(abf0, pt0);
    if (s + 2 < NSTEP) ISSUEF(aA0,aA1,pA0,pA1, (s+2)*128);
    STAGEF(abf1, pt1, aB0,aB1, pB0,pB1);
    SYNC_AND();
    compute(abf1, pt1);
  }

  // fused blend epilogue: exclusive ownership of out[:, n0+wn*16+(l&15)]
  {
    int col = n0 + wn*16 + (l & 15);
    float ib = fmaxf(I_B[col], 0.f);
    #pragma unroll
    for (int q = 0; q < 4; q++){
      int row = wm*16 + (l >> 4)*4 + q;
      float pv = bf2f(pbf[(size_t)row*N_ + col]);
      float cv = fmaxf(acc[q], 0.f);
      out[(size_t)row*N_ + col] = 0.5f*pv + 0.5f*(pv*ib + cv);
    }
  }
}

extern "C" void kernel_launch(void* const* d_in, const int* in_sizes, int n_in,
                              void* d_out, int out_size, void* d_ws, size_t ws_size,
                              hipStream_t stream) {
  const float* x     = (const float*)d_in[0];
  const int*   seq   = (const int*)  d_in[1];
  const float* A     = (const float*)d_in[2];
  const float* W1    = (const float*)d_in[3];
  const float* b1    = (const float*)d_in[4];
  const float* W2    = (const float*)d_in[5];
  const float* b2    = (const float*)d_in[6];
  const float* W_ih  = (const float*)d_in[7];
  const float* W_hh  = (const float*)d_in[8];
  const float* b_ih  = (const float*)d_in[9];
  const float* b_hh  = (const float*)d_in[10];
  const float* W_out = (const float*)d_in[11];
  const float* I_B   = (const float*)d_in[12];
  float* out = (float*)d_out;

  float* ws = (float*)d_ws;
  unsigned short* W12T = (unsigned short*)ws;            // 8192*256 bf16 = 1,048,576 f
  float* basket = ws + 1048576;                          // 1280*128 = 163,840 f
  float* hn     = basket + 163840;                       // 64*128   =   8,192 f
  unsigned short* pbf = (unsigned short*)(hn + 8192);    // 64*8192 bf16

  k_transpose<<<256, 256, 0, stream>>>(W1, W2, W12T);
  k_mlp      <<<1280,256, 0, stream>>>(x, seq, W12T, b1, b2, basket);
  k_lstmx    <<<64,  512, 0, stream>>>(seq, basket, W_ih, b_ih, b_hh, W_hh, hn);
  k_pout     <<<64,  256, 0, stream>>>(hn, W_out, pbf);
  k_gemmf    <<<256, 512, 0, stream>>>(pbf, A, I_B, out);
}